// Round 4
// baseline (42.268 us; speedup 1.0000x reference)
//
#include <hip/hip_runtime.h>
#include <hip/hip_bf16.h>

#define LATENT 16
#define STATE  16
#define NPOS   (64 * 8192)
#define NTILES (NPOS / 16)        // 32768 tiles of 16 positions
#define NCHUNK 9                  // K = 288 = 9 * 32
#define TPW    8                  // tiles per wave

typedef __attribute__((ext_vector_type(4))) float f32x4;
typedef __attribute__((ext_vector_type(8))) short bf16x8;  // 8 bf16 in 4 VGPRs

static __device__ __forceinline__ short f2bf(float f) {
    __hip_bfloat16 h = __float2bfloat16(f);
    return (short)__builtin_bit_cast(unsigned short, h);
}

// ---------------- prep: pack W into MFMA B-fragment order ----------------
// ws layout: [0..15] f32 bias (const-term row); then 4608 ushort Wpack.
// Wpack[(c*64 + lane)*8 + jj] = bf16 W'[k = c*32 + (lane>>4)*8 + jj][col = lane&15]
// New K order: k<256: x_I * x_J, I=k>>4, J=k&15 (off-diag weights halved);
//              k=256..271: linear x[k-256]; k=272..287: sin(x[k-272]).
__global__ __launch_bounds__(256) void prep_pack(const float* __restrict__ coef,
                                                 const float* __restrict__ mask,
                                                 float* __restrict__ wsf) {
    int id = blockIdx.x * 256 + threadIdx.x;
    if (id < 16) wsf[id] = coef[id] * mask[id];   // bias: ref row 0 (const)
    if (id >= 4608) return;
    int jj  = id & 7;
    int col = (id >> 3) & 15;
    int g   = (id >> 7) & 3;
    int c   = id >> 9;                    // 0..8
    int k   = c * 32 + g * 8 + jj;        // 0..287
    float scale = 1.0f;
    int row;
    if (k < 256) {
        int I = k >> 4, J = k & 15;
        int im = I < J ? I : J, jm = I < J ? J : I;
        int q = im * 16 - im * (im - 1) / 2 + (jm - im);  // comb_w_r index
        row = 17 + q;
        if (I != J) scale = 0.5f;
    } else if (k < 272) {
        row = 1 + (k - 256);
    } else {
        row = 153 + (k - 272);
    }
    float w = coef[row * STATE + col] * mask[row * STATE + col] * scale;
    ((ushort*)(wsf + 16))[id] = (ushort)f2bf(w);
}

// ---------------- main: theta-on-the-fly MFMA GEMM ----------------
// One wave per 8-tile stream, double-buffered private LDS, no __syncthreads.
// LDS row stride 20 floats: b128 reads at col*20 hit 8 distinct bank-groups
// (col*5 mod 8 is a bijection over 8), 2-way aliasing only (free, m136).
__global__ __launch_bounds__(256, 4) void sindy_mfma(const float* __restrict__ x,
                                                     const float* __restrict__ wsf,
                                                     float* __restrict__ out) {
    const int lane  = threadIdx.x & 63;
    const int wid   = threadIdx.x >> 6;
    const int g     = lane >> 4;          // K-slice group 0..3
    const int col   = lane & 15;          // A-row (position in tile) and D-col
    const int j0    = (g & 1) * 8;        // J-half this lane multiplies
    const int ihalf = g >> 1;             // I parity this lane covers

    // B fragments: wave-wide resident, loaded once (9 x 16B per lane)
    const ushort* Wpack = (const ushort*)(wsf + 16);
    bf16x8 bfrag[NCHUNK];
    #pragma unroll
    for (int c = 0; c < NCHUNK; ++c)
        bfrag[c] = *(const bf16x8*)(Wpack + (c * 64 + lane) * 8);

    const float bias = wsf[col];

    __shared__ float lds[4][2][16 * 20];  // [wave][dbuf][pos*20]
    const float4* x4 = (const float4*)x;

    const int wave_gid = blockIdx.x * 4 + wid;   // 4096 waves
    const int tile0 = wave_gid * TPW;

    float4 nxt = x4[(long)tile0 * 64 + lane];
    #pragma unroll
    for (int t = 0; t < TPW; ++t) {
        const int tile = tile0 + t;
        float* myl = lds[wid][t & 1];
        // stage 16 pos x 16 floats; padded-stride write (2-way max, free)
        *(float4*)&myl[(lane >> 2) * 20 + (lane & 3) * 4] = nxt;
        if (t < TPW - 1) nxt = x4[(long)(tile + 1) * 64 + lane];  // prefetch

        // full row for this lane's A-role: 4 x ds_read_b128, conflict-free
        float row[16];
        #pragma unroll
        for (int q = 0; q < 4; ++q)
            *(float4*)&row[q * 4] = *(const float4*)&myl[col * 20 + q * 4];

        f32x4 acc = {bias, bias, bias, bias};

        // quad chunks: A[col][c*32 + g*8 + jj] = x[2c+ihalf] * x[j0+jj]
        #pragma unroll
        for (int c = 0; c < 8; ++c) {
            const float xi = row[2 * c + ihalf];
            bf16x8 a;
            #pragma unroll
            for (int j = 0; j < 8; ++j) a[j] = f2bf(xi * row[j0 + j]);
            acc = __builtin_amdgcn_mfma_f32_16x16x32_bf16(a, bfrag[c], acc, 0, 0, 0);
        }
        // chunk 8: g<2 -> linear x[j0+jj]; g>=2 -> sin(x[j0+jj])
        {
            bf16x8 a;
            #pragma unroll
            for (int j = 0; j < 8; ++j) {
                float v = row[j0 + j];
                float s = __sinf(v);
                a[j] = f2bf(g >= 2 ? s : v);
            }
            acc = __builtin_amdgcn_mfma_f32_16x16x32_bf16(a, bfrag[8], acc, 0, 0, 0);
        }

        // D: row = g*4 + r (position), col = state
        #pragma unroll
        for (int r = 0; r < 4; ++r)
            out[(long)(tile * 16 + g * 4 + r) * STATE + col] = acc[r];
    }
}

extern "C" void kernel_launch(void* const* d_in, const int* in_sizes, int n_in,
                              void* d_out, int out_size, void* d_ws, size_t ws_size,
                              hipStream_t stream) {
    const float* x    = (const float*)d_in[0];
    const float* coef = (const float*)d_in[1];
    const float* mask = (const float*)d_in[2];
    float*       wsf  = (float*)d_ws;     // 16 f32 bias + 4608 ushort Wpack
    float*       out  = (float*)d_out;

    prep_pack<<<18, 256, 0, stream>>>(coef, mask, wsf);
    sindy_mfma<<<NTILES / (4 * TPW), 256, 0, stream>>>(x, wsf, out);  // 1024 blocks
}